// Round 11
// baseline (74.963 us; speedup 1.0000x reference)
//
#include <hip/hip_runtime.h>
#include <hip/hip_fp16.h>

#define IN_F    512
#define NC      4096
#define OUT_COLS 640
#define B_SZ    128
#define KD      32
#define MOH_PITCH 72    // half pitch: 144B rows, 16B-aligned, mi-broadcast conflict-free

typedef __attribute__((ext_vector_type(8))) short  bf16x8;
typedef __attribute__((ext_vector_type(4))) float  f32x4;

union FragAB { unsigned int u[4]; bf16x8 s; };
union H2x4   { uint4 u4; __half2 h[4]; };

static __device__ __forceinline__ unsigned short f2bfu(float f) {
    return (unsigned short)(__float_as_uint(f) >> 16);
}
static __device__ __forceinline__ unsigned int pack2(float lo, float hi) {
    return (__float_as_uint(lo) >> 16) | (__float_as_uint(hi) & 0xFFFF0000u);
}
static __device__ __forceinline__ __half2 habs2_(__half2 v) {
    unsigned int u = *(unsigned int*)&v & 0x7FFF7FFFu;
    return *(__half2*)&u;
}

// ONE kernel. Block (o, jhalf): stage T-strip (frag-ordered bf16, whole K) ->
// dual-nt MFMA (A inline from x, R6-verified pack) -> mo in fp16 -> pairwise.
// 3 barriers total; no workspace; no inter-kernel edges.
__global__ __launch_bounds__(512, 2) void fused_kernel(
    const float* __restrict__ x,            // fp32 [128][512]
    const float* __restrict__ T,            // fp32 [512][4096]
    float* __restrict__ out)                // fp32 [128][640]
{
    __shared__ unsigned short bs[2 * 16 * 64 * 8];  // 32 KB frag-ordered B
    __shared__ __half moh[B_SZ * MOH_PITCH];        // 18 KB fp16 m-strip
    __shared__ float psum[2 * 32 * 17];             // 4.25 KB

    const int tid   = threadIdx.x;
    const int lane  = tid & 63;
    const int mt    = tid >> 6;             // wave 0..7 = m-tile
    const int col   = lane & 15;
    const int q     = lane >> 4;
    const int o     = blockIdx.x >> 1;
    const int jhalf = blockIdx.x & 1;

    // fused x -> out[:, :512] copy (bit-exact)
    if (tid < 64) {
        int idx = blockIdx.x * 64 + tid;
        int b = idx >> 7, c4 = idx & 127;
        float4 v = ((const float4*)x)[idx];
        *(float4*)(out + b * OUT_COLS + c4 * 4) = v;
    }

    // ---- stage B: T[:, o*32..+32] -> frag-ordered bs (whole K=512) ----
    #pragma unroll
    for (int p = 0; p < 8; ++p) {
        int u  = tid + p * 512;             // float4 unit 0..4095
        int kk = u >> 3, cq = u & 7;
        float4 v = *(const float4*)(T + (size_t)kk * NC + o * 32 + cq * 4);
        int kt = kk >> 5, qq = (kk >> 3) & 3, j = kk & 7;
        float e[4] = {v.x, v.y, v.z, v.w};
        #pragma unroll
        for (int r = 0; r < 4; ++r) {
            int nn = cq * 4 + r;            // col-in-strip 0..31
            int slot = (((nn >> 4) * 16 + kt) * 64) + qq * 16 + (nn & 15);
            bs[slot * 8 + j] = f2bfu(e[r]);
        }
    }
    __syncthreads();                        // barrier 1

    // ---- MFMA: wave mt does BOTH nt tiles; A inline from x ----
    f32x4 acc0 = {0.f, 0.f, 0.f, 0.f}, acc1 = {0.f, 0.f, 0.f, 0.f};
    const float* xrow = x + (size_t)(mt * 16 + col) * IN_F + q * 8;
    #pragma unroll 8
    for (int kt = 0; kt < 16; ++kt) {
        float4 a0 = *(const float4*)(xrow + kt * 32);
        float4 a1 = *(const float4*)(xrow + kt * 32 + 4);
        FragAB af;
        af.u[0] = pack2(a0.x, a0.y); af.u[1] = pack2(a0.z, a0.w);
        af.u[2] = pack2(a1.x, a1.y); af.u[3] = pack2(a1.z, a1.w);
        bf16x8 b0 = *(const bf16x8*)&bs[((kt      ) * 64 + lane) * 8];
        bf16x8 b1 = *(const bf16x8*)&bs[((16 + kt) * 64 + lane) * 8];
        acc0 = __builtin_amdgcn_mfma_f32_16x16x32_bf16(af.s, b0, acc0, 0, 0, 0);
        acc1 = __builtin_amdgcn_mfma_f32_16x16x32_bf16(af.s, b1, acc1, 0, 0, 0);
    }
    // epilogue -> fp16 mo. C/D: row = q*4+r, col = lane&15 (verified mapping)
    {
        const int rowb = mt * 16 + q * 4;
        #pragma unroll
        for (int r = 0; r < 4; ++r) {
            moh[(rowb + r) * MOH_PITCH + col]      = __float2half(acc0[r]);
            moh[(rowb + r) * MOH_PITCH + 16 + col] = __float2half(acc1[r]);
        }
    }
    __syncthreads();                        // barrier 2

    // ---- Phase 2: o_b[j][o] = sum_i exp(-L1(m_i,m_j)) - 1, fp16-packed ----
    const int jj5 = tid & 31;
    const int isl = tid >> 4 >> 1;          // tid>>5: 0..15, i-range isl*8..+8
    const int j0  = jhalf * 64 + jj5;

    __half2 mj0[16], mj1[16];
    #pragma unroll
    for (int k16 = 0; k16 < 4; ++k16) {     // one-time, ~4-way conflict
        H2x4 a, b;
        a.u4 = *(const uint4*)&moh[j0 * MOH_PITCH + k16 * 8];
        b.u4 = *(const uint4*)&moh[(j0 + 32) * MOH_PITCH + k16 * 8];
        #pragma unroll
        for (int h = 0; h < 4; ++h) { mj0[k16*4+h] = a.h[h]; mj1[k16*4+h] = b.h[h]; }
    }

    float s0 = 0.f, s1 = 0.f;
    #pragma unroll
    for (int ii = 0; ii < 8; ++ii) {
        const int i = isl * 8 + ii;
        __half2 n0 = __float2half2_rn(0.f), n1 = __float2half2_rn(0.f);
        #pragma unroll
        for (int k16 = 0; k16 < 4; ++k16) { // 2-addr broadcast, conflict-free
            H2x4 mi; mi.u4 = *(const uint4*)&moh[i * MOH_PITCH + k16 * 8];
            #pragma unroll
            for (int h = 0; h < 4; ++h) {
                n0 = __hadd2(n0, habs2_(__hsub2(mj0[k16*4+h], mi.h[h])));
                n1 = __hadd2(n1, habs2_(__hsub2(mj1[k16*4+h], mi.h[h])));
            }
        }
        float2 f0 = __half22float2(n0), f1 = __half22float2(n1);
        s0 += __expf(-(f0.x + f0.y));       // i==j: bits identical -> norm exactly 0
        s1 += __expf(-(f1.x + f1.y));
    }
    psum[jj5 * 17 + isl]       = s0;
    psum[544 + jj5 * 17 + isl] = s1;
    __syncthreads();                        // barrier 3
    if (tid < 64) {
        int jsel = tid >> 5, jj = tid & 31;
        float tot = 0.f;
        #pragma unroll
        for (int u = 0; u < 16; ++u) tot += psum[jsel * 544 + jj * 17 + u];
        out[(jhalf * 64 + jsel * 32 + jj) * OUT_COLS + IN_F + o] = tot - 1.0f;
    }
}

extern "C" void kernel_launch(void* const* d_in, const int* in_sizes, int n_in,
                              void* d_out, int out_size, void* d_ws, size_t ws_size,
                              hipStream_t stream) {
    const float* x = (const float*)d_in[0];
    const float* T = (const float*)d_in[1];
    float* out = (float*)d_out;
    (void)d_ws; (void)ws_size;

    fused_kernel<<<256, 512, 0, stream>>>(x, T, out);
}

// Round 12
// 71.273 us; speedup vs baseline: 1.0518x; 1.0518x over previous
//
#include <hip/hip_runtime.h>
#include <hip/hip_fp16.h>

#define IN_F    512
#define NC      4096
#define OUT_COLS 640
#define B_SZ    128
#define MOH_PITCH 72    // half pitch: 144B rows, 16B-aligned

typedef __attribute__((ext_vector_type(8))) short  bf16x8;
typedef __attribute__((ext_vector_type(4))) float  f32x4;

union H2x4 { uint4 u4; __half2 h[4]; };

static __device__ __forceinline__ unsigned short f2bfu(float f) {
    return (unsigned short)(__float_as_uint(f) >> 16);
}
static __device__ __forceinline__ unsigned int pack2(float lo, float hi) {
    return (__float_as_uint(lo) >> 16) | (__float_as_uint(hi) & 0xFFFF0000u);
}
static __device__ __forceinline__ __half2 habs2_(__half2 v) {
    unsigned int u = *(unsigned int*)&v & 0x7FFF7FFFu;
    return *(__half2*)&u;
}

// prep: ONE coalesced float4 read serves both the x->out copy and the xa
// fragment pack (row=b, k=4*c4 -> frag slot algebra below). No scattered reads.
// xa[slot*8+e] = bf16(x[(mt*16+col)*512 + kt*32 + q*8 + e]), slot=(mt*16+kt)*64+q*16+col
__global__ __launch_bounds__(256) void prep_kernel(
    const float* __restrict__ x, float* __restrict__ out,
    unsigned short* __restrict__ xa)
{
    const int g = blockIdx.x * 256 + threadIdx.x;   // float4 unit, 0..16383
    const int b = g >> 7, c4 = g & 127;
    float4 v = ((const float4*)x)[g];
    *(float4*)(out + b * OUT_COLS + c4 * 4) = v;
    // row=b -> mt=b>>4, col=b&15 ; k=4*c4 -> kt=c4>>3, q=(c4>>1)&3, e0=(c4&1)*4
    const int slot = ((b >> 4) * 16 + (c4 >> 3)) * 64 + ((c4 >> 1) & 3) * 16 + (b & 15);
    uint2 pv; pv.x = pack2(v.x, v.y); pv.y = pack2(v.z, v.w);
    *(uint2*)(xa + (size_t)slot * 8 + (c4 & 1) * 4) = pv;   // 8B-aligned
}

// Fused: block (o, jhalf). Phase 1 = R10's proven GEMM (B staged once frag-ordered,
// A-frags coalesced from global xa, 16x MFMA, 3 barriers). Phase 2 = fp16-packed
// pairwise (R11-verified arithmetic) at 1024 threads.
__global__ __launch_bounds__(1024) void fused_kernel(
    const unsigned short* __restrict__ xa,  // bf16 frags of x (L2-resident)
    const float* __restrict__ T,            // fp32 [512][4096]
    float* __restrict__ out)                // fp32 [128][640]
{
    __shared__ unsigned short bs[2 * 16 * 64 * 8];      // 32 KB frag-ordered B
    __shared__ __align__(16) __half moh[B_SZ * MOH_PITCH];  // 18 KB fp16 m-strip
    __shared__ float psum[2 * 32 * 33];                 // 8.25 KB

    const int tid   = threadIdx.x;
    const int lane  = tid & 63;
    const int w     = tid >> 6;             // wave 0..15
    const int col   = lane & 15;
    const int q     = lane >> 4;
    const int o     = blockIdx.x >> 1;
    const int jhalf = blockIdx.x & 1;
    const int mt    = w >> 1, nt = w & 1;

    // ---- stage B: T[:, o*32..+32] -> frag-ordered bs (whole K=512) ----
    #pragma unroll
    for (int p = 0; p < 4; ++p) {
        int u  = tid + p * 1024;            // float4 unit 0..4095
        int kk = u >> 3, cq = u & 7;
        float4 v = *(const float4*)(T + (size_t)kk * NC + o * 32 + cq * 4);
        int kt = kk >> 5, qq = (kk >> 3) & 3, j = kk & 7;
        float e[4] = {v.x, v.y, v.z, v.w};
        #pragma unroll
        for (int r = 0; r < 4; ++r) {
            int nn = cq * 4 + r;            // col-in-strip 0..31
            int slot = (((nn >> 4) * 16 + kt) * 64) + qq * 16 + (nn & 15);
            bs[slot * 8 + j] = f2bfu(e[r]);
        }
    }
    __syncthreads();                        // barrier 1

    // ---- MFMA loop: 16 x (global A-frag 1KB coalesced + LDS b128 + MFMA) ----
    f32x4 acc = {0.f, 0.f, 0.f, 0.f};
    const unsigned short* pa = xa + ((size_t)(mt * 16) * 64 + lane) * 8;
    const unsigned short* pb = bs + ((size_t)(nt * 16) * 64 + lane) * 8;
    #pragma unroll 4
    for (int kt = 0; kt < 16; ++kt) {
        bf16x8 af  = *(const bf16x8*)(pa + (size_t)kt * 512);
        bf16x8 bfr = *(const bf16x8*)(pb + (size_t)kt * 512);   // conflict-free b128
        acc = __builtin_amdgcn_mfma_f32_16x16x32_bf16(af, bfr, acc, 0, 0, 0);
    }
    // epilogue -> fp16 moh. C/D: row = q*4+r, col = lane&15 (verified mapping)
    {
        const int rowb = mt * 16 + q * 4;
        #pragma unroll
        for (int r = 0; r < 4; ++r)
            moh[(rowb + r) * MOH_PITCH + nt * 16 + col] = __float2half(acc[r]);
    }
    __syncthreads();                        // barrier 2

    // ---- Phase 2: o_b[j][o] = sum_i exp(-L1(m_i,m_j)) - 1, fp16-packed ----
    const int jj5 = tid & 31;
    const int isl = tid >> 5;               // 0..31, i-range = isl*4..+4
    const int j0  = jhalf * 64 + jj5;

    __half2 mj0[16], mj1[16];
    #pragma unroll
    for (int k16 = 0; k16 < 4; ++k16) {     // one-time strided reads
        H2x4 a, b;
        a.u4 = *(const uint4*)&moh[j0 * MOH_PITCH + k16 * 8];
        b.u4 = *(const uint4*)&moh[(j0 + 32) * MOH_PITCH + k16 * 8];
        #pragma unroll
        for (int h = 0; h < 4; ++h) { mj0[k16*4+h] = a.h[h]; mj1[k16*4+h] = b.h[h]; }
    }

    float s0 = 0.f, s1 = 0.f;
    #pragma unroll
    for (int ii = 0; ii < 4; ++ii) {
        const int i = isl * 4 + ii;
        __half2 n0 = __float2half2_rn(0.f), n1 = __float2half2_rn(0.f);
        #pragma unroll
        for (int k16 = 0; k16 < 4; ++k16) { // broadcast b128, conflict-free
            H2x4 mi; mi.u4 = *(const uint4*)&moh[i * MOH_PITCH + k16 * 8];
            #pragma unroll
            for (int h = 0; h < 4; ++h) {
                n0 = __hadd2(n0, habs2_(__hsub2(mj0[k16*4+h], mi.h[h])));
                n1 = __hadd2(n1, habs2_(__hsub2(mj1[k16*4+h], mi.h[h])));
            }
        }
        float2 f0 = __half22float2(n0), f1 = __half22float2(n1);
        s0 += __expf(-(f0.x + f0.y));       // i==j: identical bits -> norm exactly 0
        s1 += __expf(-(f1.x + f1.y));
    }
    psum[jj5 * 33 + isl]        = s0;       // pitch 33 -> conflict-free
    psum[1056 + jj5 * 33 + isl] = s1;
    __syncthreads();                        // barrier 3
    if (tid < 64) {
        int jsel = tid >> 5, jj = tid & 31;
        float tot = 0.f;
        #pragma unroll
        for (int u = 0; u < 32; ++u) tot += psum[jsel * 1056 + jj * 33 + u];
        out[(jhalf * 64 + jsel * 32 + jj) * OUT_COLS + IN_F + o] = tot - 1.0f;
    }
}

extern "C" void kernel_launch(void* const* d_in, const int* in_sizes, int n_in,
                              void* d_out, int out_size, void* d_ws, size_t ws_size,
                              hipStream_t stream) {
    const float* x = (const float*)d_in[0];
    const float* T = (const float*)d_in[1];
    float* out = (float*)d_out;
    unsigned short* xa = (unsigned short*)d_ws;     // 256 KB

    prep_kernel<<<64, 256, 0, stream>>>(x, out, xa);
    fused_kernel<<<256, 1024, 0, stream>>>(xa, T, out);
}

// Round 13
// 69.941 us; speedup vs baseline: 1.0718x; 1.0191x over previous
//
#include <hip/hip_runtime.h>
#include <hip/hip_fp16.h>

#define IN_F    512
#define NC      4096
#define OUT_COLS 640
#define B_SZ    128
#define MOH_PITCH 72    // half pitch: 144B rows

typedef __attribute__((ext_vector_type(8)))  short bf16x8;
typedef __attribute__((ext_vector_type(16))) float f32x16;

union H2x4  { uint4 u4; __half2 h[4]; };
union FragB { unsigned int u[4]; bf16x8 s; };

static __device__ __forceinline__ unsigned int pack2(float lo, float hi) {
    return (__float_as_uint(lo) >> 16) | (__float_as_uint(hi) & 0xFFFF0000u);
}
static __device__ __forceinline__ __half2 habs2_(__half2 v) {
    unsigned int u = *(unsigned int*)&v & 0x7FFF7FFFu;
    return *(__half2*)&u;
}

// prep: ONE coalesced float4 read -> x->out copy + xa pack for the 32-row A layout:
// xa[((mt*32+kc)*64 + khalf*32 + row31)*8 + e], mt=row>>5, kc=k>>4, khalf=(k>>3)&1, e=k&7
__global__ __launch_bounds__(256) void prep_kernel(
    const float* __restrict__ x, float* __restrict__ out,
    unsigned short* __restrict__ xa)
{
    const int g = blockIdx.x * 256 + threadIdx.x;   // float4 unit, 0..16383
    const int b = g >> 7, c4 = g & 127;
    float4 v = ((const float4*)x)[g];
    *(float4*)(out + b * OUT_COLS + c4 * 4) = v;
    const int slot = ((b >> 5) * 32 + (c4 >> 2)) * 64 + ((c4 >> 1) & 1) * 32 + (b & 31);
    uint2 pv; pv.x = pack2(v.x, v.y); pv.y = pack2(v.z, v.w);
    *(uint2*)(xa + (size_t)slot * 8 + (c4 & 1) * 4) = pv;
}

// Fused, no B-LDS: block (o=bid&127, jhalf=bid>>7) -> jhalf pair shares XCD L2 for T.
// Wave (mt, kg): 32x32 tile rows mt*32.., K-range kg*128.. via mfma_32x32x16_bf16;
// A from frag-ordered xa (1KB/wave coalesced), B direct from T (2-line insts, L1-reused).
// K-partials reduced through 64KB LDS (conflict-free), overlaid by moh/psum.
__global__ __launch_bounds__(1024) void fused_kernel(
    const unsigned short* __restrict__ xa,
    const float* __restrict__ T,
    float* __restrict__ out)
{
    __shared__ __align__(16) char smem[65536];
    float*  red  = (float*)smem;                    // [kg][mt][row][col] fp32, 64 KB
    __half* moh  = (__half*)smem;                   // overlay after barrier 2
    float*  psum = (float*)(smem + 18432);          // after moh (18432 B)

    const int tid    = threadIdx.x;
    const int lane   = tid & 63;
    const int w      = tid >> 6;            // wave 0..15
    const int o      = blockIdx.x & 127;
    const int jhalf  = blockIdx.x >> 7;
    const int mt     = w & 3;               // rows mt*32..+31
    const int kg     = w >> 2;              // K kg*128..+127
    const int col    = lane & 31;
    const int half32 = lane >> 5;           // 0/1

    // ---- Phase 1: per-wave 32x32 MFMA over K=128, no LDS, no barriers ----
    f32x16 acc = {0.f,0.f,0.f,0.f,0.f,0.f,0.f,0.f,0.f,0.f,0.f,0.f,0.f,0.f,0.f,0.f};
    const unsigned short* pa = xa + ((size_t)(mt * 32 + kg * 8) * 64 + lane) * 8;
    const float* pb = T + (size_t)(kg * 128 + half32 * 8) * NC + o * 32 + col;
    #pragma unroll
    for (int ch = 0; ch < 8; ++ch) {        // 8 chunks of K=16
        bf16x8 af = *(const bf16x8*)(pa + (size_t)ch * 512);
        const float* tb = pb + (size_t)ch * 16 * NC;
        float b0 = tb[0*NC], b1 = tb[1*NC], b2 = tb[2*NC], b3 = tb[3*NC];
        float b4 = tb[4*NC], b5 = tb[5*NC], b6 = tb[6*NC], b7 = tb[7*NC];
        FragB bf;
        bf.u[0] = pack2(b0, b1); bf.u[1] = pack2(b2, b3);
        bf.u[2] = pack2(b4, b5); bf.u[3] = pack2(b6, b7);
        acc = __builtin_amdgcn_mfma_f32_32x32x16_bf16(af, bf.s, acc, 0, 0, 0);
    }
    // partials -> red. C/D (m74/m101-verified): col=lane&31, row=(r&3)+8*(r>>2)+4*half32
    {
        float* rd = red + kg * 4096 + mt * 1024 + col;
        #pragma unroll
        for (int r = 0; r < 16; ++r) {
            int row = (r & 3) + 8 * (r >> 2) + 4 * half32;
            rd[row * 32] = acc[r];          // banks: 2 lanes/bank -> free
        }
    }
    __syncthreads();                        // barrier 1

    // ---- reduce 4 K-partials (reads), then overlay-write moh as fp16 ----
    float4 s;
    {
        const int e = tid * 4;
        s = *(const float4*)&red[e];
        #pragma unroll
        for (int p = 1; p < 4; ++p) {
            float4 v2 = *(const float4*)&red[p * 4096 + e];
            s.x += v2.x; s.y += v2.y; s.z += v2.z; s.w += v2.w;
        }
    }
    __syncthreads();                        // barrier 2: all red reads done
    {
        const int e = tid * 4;
        const int mtt = e >> 10, row = (e >> 5) & 31, c0 = e & 31;
        __half2 lo = __floats2half2_rn(s.x, s.y);
        __half2 hi = __floats2half2_rn(s.z, s.w);
        uint2 w2; w2.x = *(unsigned int*)&lo; w2.y = *(unsigned int*)&hi;
        *(uint2*)&moh[(mtt * 32 + row) * MOH_PITCH + c0] = w2;
    }
    __syncthreads();                        // barrier 3

    // ---- Phase 2: o_b[j][o] = sum_i exp(-L1(m_i,m_j)) - 1 (R12-verified) ----
    const int jj5 = tid & 31;
    const int isl = tid >> 5;               // 0..31, i-range isl*4..+4
    const int j0  = jhalf * 64 + jj5;

    __half2 mj0[16], mj1[16];
    #pragma unroll
    for (int k16 = 0; k16 < 4; ++k16) {
        H2x4 a, b;
        a.u4 = *(const uint4*)&moh[j0 * MOH_PITCH + k16 * 8];
        b.u4 = *(const uint4*)&moh[(j0 + 32) * MOH_PITCH + k16 * 8];
        #pragma unroll
        for (int h = 0; h < 4; ++h) { mj0[k16*4+h] = a.h[h]; mj1[k16*4+h] = b.h[h]; }
    }

    float s0 = 0.f, s1 = 0.f;
    #pragma unroll
    for (int ii = 0; ii < 4; ++ii) {
        const int i = isl * 4 + ii;
        __half2 n0 = __float2half2_rn(0.f), n1 = __float2half2_rn(0.f);
        #pragma unroll
        for (int k16 = 0; k16 < 4; ++k16) {
            H2x4 mi; mi.u4 = *(const uint4*)&moh[i * MOH_PITCH + k16 * 8];
            #pragma unroll
            for (int h = 0; h < 4; ++h) {
                n0 = __hadd2(n0, habs2_(__hsub2(mj0[k16*4+h], mi.h[h])));
                n1 = __hadd2(n1, habs2_(__hsub2(mj1[k16*4+h], mi.h[h])));
            }
        }
        float2 f0 = __half22float2(n0), f1 = __half22float2(n1);
        s0 += __expf(-(f0.x + f0.y));       // i==j: identical bits -> norm exactly 0
        s1 += __expf(-(f1.x + f1.y));
    }
    psum[jj5 * 33 + isl]        = s0;
    psum[1056 + jj5 * 33 + isl] = s1;
    __syncthreads();                        // barrier 4
    if (tid < 64) {
        int jsel = tid >> 5, jj = tid & 31;
        float tot = 0.f;
        #pragma unroll
        for (int u = 0; u < 32; ++u) tot += psum[jsel * 1056 + jj * 33 + u];
        out[(jhalf * 64 + jsel * 32 + jj) * OUT_COLS + IN_F + o] = tot - 1.0f;
    }
}

extern "C" void kernel_launch(void* const* d_in, const int* in_sizes, int n_in,
                              void* d_out, int out_size, void* d_ws, size_t ws_size,
                              hipStream_t stream) {
    const float* x = (const float*)d_in[0];
    const float* T = (const float*)d_in[1];
    float* out = (float*)d_out;
    unsigned short* xa = (unsigned short*)d_ws;     // 128 KB

    prep_kernel<<<64, 256, 0, stream>>>(x, out, xa);
    fused_kernel<<<256, 1024, 0, stream>>>(xa, T, out);
}